// Round 2
// baseline (440.348 us; speedup 1.0000x reference)
//
#include <hip/hip_runtime.h>

// ---------------------------------------------------------------------------
// VenomGNN: 2-layer GAT (4 heads x 64, then 1 head x 64) + linear classifier.
// Strategy: build dst-CSR once (no output atomics), two-pass exact segment
// softmax per node (matches reference numerics), float4 row gathers,
// fused epilogues.
// ---------------------------------------------------------------------------

__device__ __forceinline__ float lrelu(float e) { return e > 0.f ? e : 0.2f * e; }
__device__ __forceinline__ float eluf(float v)  { return v > 0.f ? v : (__expf(v) - 1.f); }

// Detect whether edge_index was staged as int64 (reference dtype) or int32.
// For int64 little-endian with values < 50000, every odd 32-bit word is 0.
__global__ void k_detect(const int* __restrict__ ei32, int* __restrict__ flag) {
    int t = threadIdx.x;
    int w = ei32[2 * t + 1];
    unsigned long long b = __ballot(w != 0);
    if (t == 0) flag[0] = (b == 0ull) ? 1 : 0;  // 1 => int64
}

__device__ __forceinline__ int edge_val(const void* ei, int idx, int is64) {
    if (is64) return (int)((const long long*)ei)[idx];
    return ((const int*)ei)[idx];
}

// K1: h1 = x @ W1  [N,256]; alpha1_src/dst [N,4] via per-head wave reduction.
__global__ __launch_bounds__(256) void k1_feat(
    const float* __restrict__ x, const float* __restrict__ W1,
    const float* __restrict__ a1s_, const float* __restrict__ a1d_,
    float* __restrict__ h1, float* __restrict__ aS, float* __restrict__ aD) {
    int node = blockIdx.x;
    int j = threadIdx.x;            // 0..255 = h*64 + c
    float xv[8];
#pragma unroll
    for (int k = 0; k < 8; ++k) xv[k] = x[node * 8 + k];   // wave-uniform -> s_load
    float v = 0.f;
#pragma unroll
    for (int k = 0; k < 8; ++k) v = fmaf(xv[k], W1[k * 256 + j], v);
    h1[(size_t)node * 256 + j] = v;
    int h = j >> 6, c = j & 63;
    float ps = v * a1s_[j];
    float pd = v * a1d_[j];
#pragma unroll
    for (int off = 32; off > 0; off >>= 1) {
        ps += __shfl_down(ps, off, 64);
        pd += __shfl_down(pd, off, 64);
    }
    if (c == 0) { aS[node * 4 + h] = ps; aD[node * 4 + h] = pd; }
}

// K2: in-degree histogram over real edges.
__global__ void k2_count(const void* __restrict__ ei, int E,
                         int* __restrict__ deg, const int* __restrict__ flag) {
    int e = blockIdx.x * blockDim.x + threadIdx.x;
    int is64 = flag[0];
    if (e < E) atomicAdd(&deg[edge_val(ei, E + e, is64)], 1);
}

// K3a: per-1024-chunk exclusive scan + chunk totals.
__global__ __launch_bounds__(1024) void scan_block(
    const int* __restrict__ deg, int n, int* __restrict__ offs, int* __restrict__ bsum) {
    int t = threadIdx.x;
    int i = blockIdx.x * 1024 + t;
    int v = (i < n) ? deg[i] : 0;
    int lane = t & 63, w = t >> 6;
    int s = v;
#pragma unroll
    for (int off = 1; off < 64; off <<= 1) {
        int u = __shfl_up(s, off, 64);
        if (lane >= off) s += u;
    }
    __shared__ int wsums[16];
    if (lane == 63) wsums[w] = s;
    __syncthreads();
    if (t < 16) {
        int wv = wsums[t];
#pragma unroll
        for (int off = 1; off < 16; off <<= 1) {
            int u = __shfl_up(wv, off, 64);
            if (t >= off) wv += u;
        }
        wsums[t] = wv;
    }
    __syncthreads();
    int waveoff = (w == 0) ? 0 : wsums[w - 1];
    if (i < n) offs[i] = s + waveoff - v;          // block-local exclusive
    if (t == 1023) bsum[blockIdx.x] = s + waveoff; // block total
}

// K3b: inclusive scan of <=64 chunk totals (single wave).
__global__ void scan_small(int* __restrict__ bsum, int nb) {
    int t = threadIdx.x;
    int v = (t < nb) ? bsum[t] : 0;
#pragma unroll
    for (int off = 1; off < 64; off <<= 1) {
        int u = __shfl_up(v, off, 64);
        if (t >= off) v += u;
    }
    if (t < nb) bsum[t] = v;
}

// K3c: add chunk offsets; mirror into scatter cursors; write offs[n].
__global__ void scan_add(int* __restrict__ offs, const int* __restrict__ bsum,
                         int* __restrict__ cur, int n, int nb) {
    int i = blockIdx.x * blockDim.x + threadIdx.x;
    if (i < n) {
        int b = i >> 10;
        int val = offs[i] + (b ? bsum[b - 1] : 0);
        offs[i] = val;
        cur[i] = val;
    }
    if (i == 0) offs[n] = bsum[nb - 1];
}

// K4: bucket-scatter src ids into dst-CSR order.
__global__ void k4_scatter(const void* __restrict__ ei, int E,
                           int* __restrict__ cur, int* __restrict__ ssrc,
                           const int* __restrict__ flag) {
    int e = blockIdx.x * blockDim.x + threadIdx.x;
    int is64 = flag[0];
    if (e < E) {
        int d = edge_val(ei, E + e, is64);
        int s = edge_val(ei, e, is64);
        int p = atomicAdd(&cur[d], 1);
        ssrc[p] = s;
    }
}

// K5: GAT-1 segment softmax + aggregate + bias + ELU.
// Block = 4 nodes, wave = node. Lane c owns channels 4c..4c+3 (float4),
// head h = c>>4. One 1KB dwordx4 gather per edge per wave; x4 edge unroll.
__global__ __launch_bounds__(256) void k5_agg1(
    const float* __restrict__ h1, const float* __restrict__ aS,
    const float* __restrict__ aD, const int* __restrict__ offs,
    const int* __restrict__ ssrc, const float* __restrict__ b1,
    float* __restrict__ hout, int n) {
    int node = blockIdx.x * 4 + (threadIdx.x >> 6);
    if (node >= n) return;
    int c = threadIdx.x & 63;
    int h = c >> 4;
    int s0 = offs[node], s1 = offs[node + 1];
    float ad = aD[node * 4 + h];
    float lself = lrelu(aS[node * 4 + h] + ad);
    // pass 1: group-parallel max over incoming edges (+ self loop)
    float m = lself;
    for (int e = s0 + (c & 15); e < s1; e += 16)
        m = fmaxf(m, lrelu(aS[ssrc[e] * 4 + h] + ad));
#pragma unroll
    for (int off = 8; off > 0; off >>= 1) m = fmaxf(m, __shfl_xor(m, off, 64));
    // pass 2: sum exp + weighted float4 row gathers (x4 unroll for VMEM ILP)
    const float4* h1v = (const float4*)h1;
    float denom = 0.f;
    float4 acc = make_float4(0.f, 0.f, 0.f, 0.f);
    int e = s0;
    for (; e + 4 <= s1; e += 4) {
        int sA = ssrc[e], sB = ssrc[e + 1], sC = ssrc[e + 2], sD = ssrc[e + 3];
        float4 hA = h1v[(size_t)sA * 64 + c];
        float4 hB = h1v[(size_t)sB * 64 + c];
        float4 hC = h1v[(size_t)sC * 64 + c];
        float4 hD = h1v[(size_t)sD * 64 + c];
        float xA = __expf(lrelu(aS[sA * 4 + h] + ad) - m);
        float xB = __expf(lrelu(aS[sB * 4 + h] + ad) - m);
        float xC = __expf(lrelu(aS[sC * 4 + h] + ad) - m);
        float xD = __expf(lrelu(aS[sD * 4 + h] + ad) - m);
        denom += (xA + xB) + (xC + xD);
        acc.x = fmaf(xA, hA.x, acc.x); acc.y = fmaf(xA, hA.y, acc.y);
        acc.z = fmaf(xA, hA.z, acc.z); acc.w = fmaf(xA, hA.w, acc.w);
        acc.x = fmaf(xB, hB.x, acc.x); acc.y = fmaf(xB, hB.y, acc.y);
        acc.z = fmaf(xB, hB.z, acc.z); acc.w = fmaf(xB, hB.w, acc.w);
        acc.x = fmaf(xC, hC.x, acc.x); acc.y = fmaf(xC, hC.y, acc.y);
        acc.z = fmaf(xC, hC.z, acc.z); acc.w = fmaf(xC, hC.w, acc.w);
        acc.x = fmaf(xD, hD.x, acc.x); acc.y = fmaf(xD, hD.y, acc.y);
        acc.z = fmaf(xD, hD.z, acc.z); acc.w = fmaf(xD, hD.w, acc.w);
    }
    for (; e < s1; ++e) {
        int s = ssrc[e];
        float4 hv = h1v[(size_t)s * 64 + c];
        float ex = __expf(lrelu(aS[s * 4 + h] + ad) - m);
        denom += ex;
        acc.x = fmaf(ex, hv.x, acc.x); acc.y = fmaf(ex, hv.y, acc.y);
        acc.z = fmaf(ex, hv.z, acc.z); acc.w = fmaf(ex, hv.w, acc.w);
    }
    float exs = __expf(lself - m);
    denom += exs;
    float4 hS = h1v[(size_t)node * 64 + c];
    acc.x = fmaf(exs, hS.x, acc.x); acc.y = fmaf(exs, hS.y, acc.y);
    acc.z = fmaf(exs, hS.z, acc.z); acc.w = fmaf(exs, hS.w, acc.w);
    float inv = 1.f / (denom + 1e-16f);
    float4 bv = ((const float4*)b1)[c];
    float4 o;
    o.x = eluf(fmaf(acc.x, inv, bv.x));
    o.y = eluf(fmaf(acc.y, inv, bv.y));
    o.z = eluf(fmaf(acc.z, inv, bv.z));
    o.w = eluf(fmaf(acc.w, inv, bv.w));
    ((float4*)hout)[(size_t)node * 64 + c] = o;
}

// K6: h2 = hout @ W2  ([N,256]x[256,64]) + fused alpha2 reductions.
// 32 nodes/block; W2 staged in LDS in two 32KB halves; 8-node register reuse.
__global__ __launch_bounds__(256) void k6_gemm(
    const float* __restrict__ hin, const float* __restrict__ W2,
    const float* __restrict__ a2s, const float* __restrict__ a2d,
    float* __restrict__ h2, float* __restrict__ A2S, float* __restrict__ A2D,
    int n) {
    __shared__ float W2s[128 * 64];  // 32 KB
    __shared__ float hs[32 * 256];   // 32 KB
    int tid = threadIdx.x;
    int nb0 = blockIdx.x * 32;
    for (int i = tid; i < 2048; i += 256) {  // 32 rows x 64 float4
        int row = i >> 6;
        int node = nb0 + row;
        float4 val = make_float4(0.f, 0.f, 0.f, 0.f);
        if (node < n) val = ((const float4*)hin)[(size_t)node * 64 + (i & 63)];
        ((float4*)hs)[i] = val;
    }
    int j = tid & 63, ng = tid >> 6;
    float acc[8];
#pragma unroll
    for (int i = 0; i < 8; ++i) acc[i] = 0.f;
    for (int kc = 0; kc < 2; ++kc) {
        __syncthreads();
        for (int i = tid; i < 2048; i += 256)
            ((float4*)W2s)[i] = ((const float4*)W2)[kc * 2048 + i];
        __syncthreads();
#pragma unroll 4
        for (int k = 0; k < 128; ++k) {
            float w = W2s[k * 64 + j];
#pragma unroll
            for (int i = 0; i < 8; ++i)
                acc[i] = fmaf(hs[(ng * 8 + i) * 256 + kc * 128 + k], w, acc[i]);
        }
    }
    float as_ = a2s[j], ad_ = a2d[j];
#pragma unroll
    for (int i = 0; i < 8; ++i) {
        int node = nb0 + ng * 8 + i;
        if (node < n) h2[(size_t)node * 64 + j] = acc[i];
        float ps = acc[i] * as_, pd = acc[i] * ad_;
#pragma unroll
        for (int off = 32; off > 0; off >>= 1) {
            ps += __shfl_down(ps, off, 64);
            pd += __shfl_down(pd, off, 64);
        }
        if (j == 0 && node < n) { A2S[node] = ps; A2D[node] = pd; }
    }
}

// K7: GAT-2 segment softmax + aggregate + bias + ELU + classifier (fused).
// Wave = node. Pass 2: lane c handles edge-group g=c>>4, channel-quad q=c&15
// (float4) -> 1KB per load instr, 4 edges in flight; xor(16,32) reduce.
__global__ __launch_bounds__(256) void k7_agg2(
    const float* __restrict__ h2, const float* __restrict__ A2S,
    const float* __restrict__ A2D, const int* __restrict__ offs,
    const int* __restrict__ ssrc, const float* __restrict__ b2,
    const float* __restrict__ Wc, const float* __restrict__ bc,
    float* __restrict__ out, int n) {
    int node = blockIdx.x * 4 + (threadIdx.x >> 6);
    if (node >= n) return;
    int c = threadIdx.x & 63;
    int s0 = offs[node], s1 = offs[node + 1];
    float ad = A2D[node];
    float lself = lrelu(A2S[node] + ad);
    float m = lself;
    for (int e = s0 + c; e < s1; e += 64) m = fmaxf(m, lrelu(A2S[ssrc[e]] + ad));
#pragma unroll
    for (int off = 32; off > 0; off >>= 1) m = fmaxf(m, __shfl_xor(m, off, 64));
    int g = c >> 4, q = c & 15;
    const float4* h2v = (const float4*)h2;
    float denom = 0.f;
    float4 acc = make_float4(0.f, 0.f, 0.f, 0.f);
    for (int e = s0 + g; e < s1; e += 4) {
        int s = ssrc[e];
        float4 hv = h2v[(size_t)s * 16 + q];
        float ex = __expf(lrelu(A2S[s] + ad) - m);
        denom += ex;
        acc.x = fmaf(ex, hv.x, acc.x); acc.y = fmaf(ex, hv.y, acc.y);
        acc.z = fmaf(ex, hv.z, acc.z); acc.w = fmaf(ex, hv.w, acc.w);
    }
    // reduce over the 4 edge-groups
#pragma unroll
    for (int off = 16; off <= 32; off <<= 1) {
        denom += __shfl_xor(denom, off, 64);
        acc.x += __shfl_xor(acc.x, off, 64);
        acc.y += __shfl_xor(acc.y, off, 64);
        acc.z += __shfl_xor(acc.z, off, 64);
        acc.w += __shfl_xor(acc.w, off, 64);
    }
    float exs = __expf(lself - m);
    denom += exs;
    float4 hS = h2v[(size_t)node * 16 + q];
    acc.x = fmaf(exs, hS.x, acc.x); acc.y = fmaf(exs, hS.y, acc.y);
    acc.z = fmaf(exs, hS.z, acc.z); acc.w = fmaf(exs, hS.w, acc.w);
    float inv = 1.f / (denom + 1e-16f);
    float4 bv = ((const float4*)b2)[q];
    float o0 = eluf(fmaf(acc.x, inv, bv.x));
    float o1 = eluf(fmaf(acc.y, inv, bv.y));
    float o2 = eluf(fmaf(acc.z, inv, bv.z));
    float o3 = eluf(fmaf(acc.w, inv, bv.w));
    int ch = q * 4;
    float p0 = o0 * Wc[ch * 2 + 0] + o1 * Wc[ch * 2 + 2] + o2 * Wc[ch * 2 + 4] + o3 * Wc[ch * 2 + 6];
    float p1 = o0 * Wc[ch * 2 + 1] + o1 * Wc[ch * 2 + 3] + o2 * Wc[ch * 2 + 5] + o3 * Wc[ch * 2 + 7];
#pragma unroll
    for (int off = 8; off > 0; off >>= 1) {
        p0 += __shfl_xor(p0, off, 64);
        p1 += __shfl_xor(p1, off, 64);
    }
    if (c == 0) {
        out[(size_t)node * 2 + 0] = p0 + bc[0];
        out[(size_t)node * 2 + 1] = p1 + bc[1];
    }
}

extern "C" void kernel_launch(void* const* d_in, const int* in_sizes, int n_in,
                              void* d_out, int out_size, void* d_ws, size_t ws_size,
                              hipStream_t stream) {
    const float* x   = (const float*)d_in[0];
    const void*  ei  = d_in[1];                 // int64 or int32, detected on device
    const float* W1  = (const float*)d_in[2];
    const float* a1s = (const float*)d_in[3];
    const float* a1d = (const float*)d_in[4];
    const float* b1  = (const float*)d_in[5];
    const float* W2  = (const float*)d_in[6];
    const float* a2s = (const float*)d_in[7];
    const float* a2d = (const float*)d_in[8];
    const float* b2  = (const float*)d_in[9];
    const float* Wc  = (const float*)d_in[10];
    const float* bc  = (const float*)d_in[11];
    float* out = (float*)d_out;
    (void)n_in; (void)out_size; (void)ws_size;

    int n = in_sizes[0] / 8;   // 50000
    int E = in_sizes[1] / 2;   // 800000

    char* ws = (char*)d_ws;
    size_t o = 0;
    auto carve = [&](size_t bytes) -> char* {
        char* p = ws + o;
        o = (o + bytes + 255) & ~(size_t)255;
        return p;
    };
    float* h1   = (float*)carve((size_t)n * 256 * 4);
    float* hout = (float*)carve((size_t)n * 256 * 4);
    float* aS   = (float*)carve((size_t)n * 4 * 4);
    float* aD   = (float*)carve((size_t)n * 4 * 4);
    int*   deg  = (int*)carve((size_t)n * 4);
    int*   offs = (int*)carve((size_t)(n + 1) * 4);
    int*   cur  = (int*)carve((size_t)n * 4);
    int*   ssrc = (int*)carve((size_t)E * 4);
    int*   bsum = (int*)carve(64 * 4);
    int*   flag = (int*)carve(64 * 4);
    float* A2S  = (float*)carve((size_t)n * 4);
    float* A2D  = (float*)carve((size_t)n * 4);
    float* h2   = h1;  // alias: h1 is dead after k5_agg1

    hipMemsetAsync(deg, 0, (size_t)n * 4, stream);
    k_detect<<<1, 64, 0, stream>>>((const int*)ei, flag);
    k1_feat<<<n, 256, 0, stream>>>(x, W1, a1s, a1d, h1, aS, aD);
    k2_count<<<(E + 255) / 256, 256, 0, stream>>>(ei, E, deg, flag);
    int nb = (n + 1023) / 1024;
    scan_block<<<nb, 1024, 0, stream>>>(deg, n, offs, bsum);
    scan_small<<<1, 64, 0, stream>>>(bsum, nb);
    scan_add<<<(n + 255) / 256, 256, 0, stream>>>(offs, bsum, cur, n, nb);
    k4_scatter<<<(E + 255) / 256, 256, 0, stream>>>(ei, E, cur, ssrc, flag);
    k5_agg1<<<(n + 3) / 4, 256, 0, stream>>>(h1, aS, aD, offs, ssrc, b1, hout, n);
    k6_gemm<<<(n + 31) / 32, 256, 0, stream>>>(hout, W2, a2s, a2d, h2, A2S, A2D, n);
    k7_agg2<<<(n + 3) / 4, 256, 0, stream>>>(h2, A2S, A2D, offs, ssrc, b2, Wc, bc, out, n);
}

// Round 5
// 322.057 us; speedup vs baseline: 1.3673x; 1.3673x over previous
//
#include <hip/hip_runtime.h>

// ---------------------------------------------------------------------------
// VenomGNN: 2-layer GAT (4 heads x 64, then 1 head x 64) + linear classifier.
// Layer-1 aggregation uses linearity of h1 = x@W1:
//   sum_e alpha*h1[src] == (sum_e alpha*x[src]) @ W1,  aS/aD = x @ (W1.a1)
// so h1 [N,256] is never materialized; per-edge gathers are 48B (x + aS,
// both L2-resident). Softmax computed without max-shift (shift-invariant;
// exponents bounded |e|<~6). dst-CSR built once, reused by both layers.
// ---------------------------------------------------------------------------

__device__ __forceinline__ float lrelu(float e) { return e > 0.f ? e : 0.2f * e; }
__device__ __forceinline__ float eluf(float v)  { return v > 0.f ? v : (__expf(v) - 1.f); }

// Per-block edge-dtype detection (int64 ref dtype vs int32 staging): for
// int64 little-endian values < 2^31, every odd 32-bit word is 0.
__device__ __forceinline__ int detect_is64(const int* __restrict__ ei32, int* s_is64) {
    if (threadIdx.x < 64) {
        int w = ei32[2 * threadIdx.x + 1];
        unsigned long long b = __ballot(w != 0);
        if (threadIdx.x == 0) *s_is64 = (b == 0ull) ? 1 : 0;
    }
    __syncthreads();
    return *s_is64;
}

// K1: aS/aD [N,4] = x @ (W1 . a1s/d), with the 8x4 folded matrices recomputed
// per block into LDS (trivial). Also zeroes deg[] (saves a memset dispatch).
__global__ __launch_bounds__(256) void k1_alpha(
    const float* __restrict__ x, const float* __restrict__ W1,
    const float* __restrict__ a1s, const float* __restrict__ a1d,
    float* __restrict__ aS, float* __restrict__ aD, int* __restrict__ deg, int n) {
    __shared__ float sA1S[32], sA1D[32];
    int t = threadIdx.x;
    if (t < 64) {
        int k = (t & 31) >> 2, h = t & 3;
        const float* av = (t < 32) ? a1s : a1d;
        float ss = 0.f;
        for (int c = 0; c < 64; ++c)
            ss = fmaf(W1[k * 256 + h * 64 + c], av[h * 64 + c], ss);
        if (t < 32) sA1S[t] = ss; else sA1D[t - 32] = ss;
    }
    __syncthreads();
    int node = blockIdx.x * 256 + t;
    if (node >= n) return;
    deg[node] = 0;
    float4 xa = ((const float4*)x)[node * 2];
    float4 xb = ((const float4*)x)[node * 2 + 1];
    float xv[8] = {xa.x, xa.y, xa.z, xa.w, xb.x, xb.y, xb.z, xb.w};
    float s[4], d[4];
#pragma unroll
    for (int h = 0; h < 4; ++h) {
        float ss = 0.f, sd = 0.f;
#pragma unroll
        for (int k = 0; k < 8; ++k) {
            ss = fmaf(xv[k], sA1S[k * 4 + h], ss);
            sd = fmaf(xv[k], sA1D[k * 4 + h], sd);
        }
        s[h] = ss; d[h] = sd;
    }
    ((float4*)aS)[node] = make_float4(s[0], s[1], s[2], s[3]);
    ((float4*)aD)[node] = make_float4(d[0], d[1], d[2], d[3]);
}

// K2: in-degree histogram over real edges (low-dword reads only).
__global__ __launch_bounds__(256) void k2_count(
    const int* __restrict__ ei32, int E, int* __restrict__ deg) {
    __shared__ int sf;
    int is64 = detect_is64(ei32, &sf);
    int e = blockIdx.x * 256 + threadIdx.x;
    if (e < E) {
        int d = is64 ? ei32[(E + e) * 2] : ei32[E + e];
        atomicAdd(&deg[d], 1);
    }
}

// K3a: per-1024-chunk exclusive scan + chunk totals.
__global__ __launch_bounds__(1024) void scan_block(
    const int* __restrict__ deg, int n, int* __restrict__ offs, int* __restrict__ bsum) {
    int t = threadIdx.x;
    int i = blockIdx.x * 1024 + t;
    int v = (i < n) ? deg[i] : 0;
    int lane = t & 63, w = t >> 6;
    int s = v;
#pragma unroll
    for (int off = 1; off < 64; off <<= 1) {
        int u = __shfl_up(s, off, 64);
        if (lane >= off) s += u;
    }
    __shared__ int wsums[16];
    if (lane == 63) wsums[w] = s;
    __syncthreads();
    if (t < 16) {
        int wv = wsums[t];
#pragma unroll
        for (int off = 1; off < 16; off <<= 1) {
            int u = __shfl_up(wv, off, 64);
            if (t >= off) wv += u;
        }
        wsums[t] = wv;
    }
    __syncthreads();
    int waveoff = (w == 0) ? 0 : wsums[w - 1];
    if (i < n) offs[i] = s + waveoff - v;          // block-local exclusive
    if (t == 1023) bsum[blockIdx.x] = s + waveoff; // block total
}

// K3b: inclusive scan of <=64 chunk totals (single wave).
__global__ void scan_small(int* __restrict__ bsum, int nb) {
    int t = threadIdx.x;
    int v = (t < nb) ? bsum[t] : 0;
#pragma unroll
    for (int off = 1; off < 64; off <<= 1) {
        int u = __shfl_up(v, off, 64);
        if (t >= off) v += u;
    }
    if (t < nb) bsum[t] = v;
}

// K3c: add chunk offsets; mirror into scatter cursors; write offs[n].
__global__ void scan_add(int* __restrict__ offs, const int* __restrict__ bsum,
                         int* __restrict__ cur, int n, int nb) {
    int i = blockIdx.x * blockDim.x + threadIdx.x;
    if (i < n) {
        int b = i >> 10;
        int val = offs[i] + (b ? bsum[b - 1] : 0);
        offs[i] = val;
        cur[i] = val;
    }
    if (i == 0) offs[n] = bsum[nb - 1];
}

// K4: bucket-scatter src ids into dst-CSR order.
__global__ __launch_bounds__(256) void k4_scatter(
    const int* __restrict__ ei32, int E, int* __restrict__ cur,
    int* __restrict__ ssrc) {
    __shared__ int sf;
    int is64 = detect_is64(ei32, &sf);
    int e = blockIdx.x * 256 + threadIdx.x;
    if (e < E) {
        int d = is64 ? ei32[(E + e) * 2] : ei32[E + e];
        int s = is64 ? ei32[e * 2] : ei32[e];
        int p = atomicAdd(&cur[d], 1);
        ssrc[p] = s;
    }
}

// K5: GAT-1 via linearity. Wave = node; lane = eslot*4 + h (16 edge slots x
// 4 heads). Accumulates vec[h][8] = sum_e exp(e)*x[src], denom[h]; xor-reduce
// across eslots; self-loop added post-reduction; out[h*64+c] =
// ELU((vec[h].W1col)*inv[h] + b1), c = lane. No max-shift (shift-invariant).
__global__ __launch_bounds__(256) void k5_agg1(
    const float* __restrict__ x, const float* __restrict__ aS,
    const float* __restrict__ aD, const int* __restrict__ offs,
    const int* __restrict__ ssrc, const float* __restrict__ W1,
    const float* __restrict__ b1, float* __restrict__ hout, int n) {
    int node = blockIdx.x * 4 + (threadIdx.x >> 6);
    if (node >= n) return;
    int lane = threadIdx.x & 63;
    int h = lane & 3, eslot = lane >> 2;
    int s0 = offs[node], s1 = offs[node + 1];
    float ad = aD[node * 4 + h];
    float denom = 0.f;
    float vec[8] = {0.f, 0.f, 0.f, 0.f, 0.f, 0.f, 0.f, 0.f};
    const float4* xv = (const float4*)x;
    for (int e = s0 + eslot; e < s1; e += 16) {
        int s = ssrc[e];
        float ex = __expf(lrelu(aS[s * 4 + h] + ad));
        denom += ex;
        float4 xa = xv[s * 2];
        float4 xb = xv[s * 2 + 1];
        vec[0] = fmaf(ex, xa.x, vec[0]); vec[1] = fmaf(ex, xa.y, vec[1]);
        vec[2] = fmaf(ex, xa.z, vec[2]); vec[3] = fmaf(ex, xa.w, vec[3]);
        vec[4] = fmaf(ex, xb.x, vec[4]); vec[5] = fmaf(ex, xb.y, vec[5]);
        vec[6] = fmaf(ex, xb.z, vec[6]); vec[7] = fmaf(ex, xb.w, vec[7]);
    }
    // reduce across the 16 edge slots (bits 2..5), preserving h (bits 0..1)
#pragma unroll
    for (int off = 4; off < 64; off <<= 1) {
        denom += __shfl_xor(denom, off, 64);
#pragma unroll
        for (int k = 0; k < 8; ++k) vec[k] += __shfl_xor(vec[k], off, 64);
    }
    // self loop (every lane adds once to its replicated copy)
    float exs = __expf(lrelu(aS[node * 4 + h] + ad));
    denom += exs;
    float4 xa = xv[node * 2];
    float4 xb = xv[node * 2 + 1];
    vec[0] = fmaf(exs, xa.x, vec[0]); vec[1] = fmaf(exs, xa.y, vec[1]);
    vec[2] = fmaf(exs, xa.z, vec[2]); vec[3] = fmaf(exs, xa.w, vec[3]);
    vec[4] = fmaf(exs, xb.x, vec[4]); vec[5] = fmaf(exs, xb.y, vec[5]);
    vec[6] = fmaf(exs, xb.z, vec[6]); vec[7] = fmaf(exs, xb.w, vec[7]);
    // broadcast per-head sums from lanes 0..3 (lane id == h, eslot 0)
    float vhk[4][8], invd[4];
#pragma unroll
    for (int hh = 0; hh < 4; ++hh) {
        invd[hh] = 1.f / (__shfl(denom, hh, 64) + 1e-16f);
#pragma unroll
        for (int k = 0; k < 8; ++k) vhk[hh][k] = __shfl(vec[k], hh, 64);
    }
    // output: channel c = lane, for each head
#pragma unroll
    for (int hh = 0; hh < 4; ++hh) {
        int j = hh * 64 + lane;
        float dot = 0.f;
#pragma unroll
        for (int k = 0; k < 8; ++k) dot = fmaf(vhk[hh][k], W1[k * 256 + j], dot);
        hout[(size_t)node * 256 + j] = eluf(fmaf(dot, invd[hh], b1[j]));
    }
}

// K6: h2 = hout @ W2  ([N,256]x[256,64]) + fused alpha2 reductions.
// 32 nodes/block; W2 staged in LDS in two 32KB halves; 8-node register reuse.
__global__ __launch_bounds__(256) void k6_gemm(
    const float* __restrict__ hin, const float* __restrict__ W2,
    const float* __restrict__ a2s, const float* __restrict__ a2d,
    float* __restrict__ h2, float* __restrict__ A2S, float* __restrict__ A2D,
    int n) {
    __shared__ float W2s[128 * 64];  // 32 KB
    __shared__ float hs[32 * 256];   // 32 KB
    int tid = threadIdx.x;
    int nb0 = blockIdx.x * 32;
    for (int i = tid; i < 2048; i += 256) {  // 32 rows x 64 float4
        int row = i >> 6;
        int node = nb0 + row;
        float4 val = make_float4(0.f, 0.f, 0.f, 0.f);
        if (node < n) val = ((const float4*)hin)[(size_t)node * 64 + (i & 63)];
        ((float4*)hs)[i] = val;
    }
    int j = tid & 63, ng = tid >> 6;
    float acc[8];
#pragma unroll
    for (int i = 0; i < 8; ++i) acc[i] = 0.f;
    for (int kc = 0; kc < 2; ++kc) {
        __syncthreads();
        for (int i = tid; i < 2048; i += 256)
            ((float4*)W2s)[i] = ((const float4*)W2)[kc * 2048 + i];
        __syncthreads();
#pragma unroll 4
        for (int k = 0; k < 128; ++k) {
            float w = W2s[k * 64 + j];
#pragma unroll
            for (int i = 0; i < 8; ++i)
                acc[i] = fmaf(hs[(ng * 8 + i) * 256 + kc * 128 + k], w, acc[i]);
        }
    }
    float as_ = a2s[j], ad_ = a2d[j];
#pragma unroll
    for (int i = 0; i < 8; ++i) {
        int node = nb0 + ng * 8 + i;
        if (node < n) h2[(size_t)node * 64 + j] = acc[i];
        float ps = acc[i] * as_, pd = acc[i] * ad_;
#pragma unroll
        for (int off = 32; off > 0; off >>= 1) {
            ps += __shfl_down(ps, off, 64);
            pd += __shfl_down(pd, off, 64);
        }
        if (j == 0 && node < n) { A2S[node] = ps; A2D[node] = pd; }
    }
}

// K7: GAT-2 segment softmax + aggregate + bias + ELU + classifier (fused).
// Wave = node; lane c: edge-group g=c>>4, channel-quad q=c&15 (float4) ->
// 4 edges in flight; xor(16,32) cross-group reduce. No max-shift.
__global__ __launch_bounds__(256) void k7_agg2(
    const float* __restrict__ h2, const float* __restrict__ A2S,
    const float* __restrict__ A2D, const int* __restrict__ offs,
    const int* __restrict__ ssrc, const float* __restrict__ b2,
    const float* __restrict__ Wc, const float* __restrict__ bc,
    float* __restrict__ out, int n) {
    int node = blockIdx.x * 4 + (threadIdx.x >> 6);
    if (node >= n) return;
    int c = threadIdx.x & 63;
    int s0 = offs[node], s1 = offs[node + 1];
    float ad = A2D[node];
    int g = c >> 4, q = c & 15;
    const float4* h2v = (const float4*)h2;
    float denom = 0.f;
    float4 acc = make_float4(0.f, 0.f, 0.f, 0.f);
    for (int e = s0 + g; e < s1; e += 4) {
        int s = ssrc[e];
        float4 hv = h2v[(size_t)s * 16 + q];
        float ex = __expf(lrelu(A2S[s] + ad));
        denom += ex;
        acc.x = fmaf(ex, hv.x, acc.x); acc.y = fmaf(ex, hv.y, acc.y);
        acc.z = fmaf(ex, hv.z, acc.z); acc.w = fmaf(ex, hv.w, acc.w);
    }
    // reduce over the 4 edge-groups (bits 4..5)
#pragma unroll
    for (int off = 16; off <= 32; off <<= 1) {
        denom += __shfl_xor(denom, off, 64);
        acc.x += __shfl_xor(acc.x, off, 64);
        acc.y += __shfl_xor(acc.y, off, 64);
        acc.z += __shfl_xor(acc.z, off, 64);
        acc.w += __shfl_xor(acc.w, off, 64);
    }
    float exs = __expf(lrelu(A2S[node] + ad));
    denom += exs;
    float4 hS = h2v[(size_t)node * 16 + q];
    acc.x = fmaf(exs, hS.x, acc.x); acc.y = fmaf(exs, hS.y, acc.y);
    acc.z = fmaf(exs, hS.z, acc.z); acc.w = fmaf(exs, hS.w, acc.w);
    float inv = 1.f / (denom + 1e-16f);
    float4 bv = ((const float4*)b2)[q];
    float o0 = eluf(fmaf(acc.x, inv, bv.x));
    float o1 = eluf(fmaf(acc.y, inv, bv.y));
    float o2 = eluf(fmaf(acc.z, inv, bv.z));
    float o3 = eluf(fmaf(acc.w, inv, bv.w));
    int ch = q * 4;
    float p0 = o0 * Wc[ch * 2 + 0] + o1 * Wc[ch * 2 + 2] + o2 * Wc[ch * 2 + 4] + o3 * Wc[ch * 2 + 6];
    float p1 = o0 * Wc[ch * 2 + 1] + o1 * Wc[ch * 2 + 3] + o2 * Wc[ch * 2 + 5] + o3 * Wc[ch * 2 + 7];
#pragma unroll
    for (int off = 8; off > 0; off >>= 1) {
        p0 += __shfl_xor(p0, off, 64);
        p1 += __shfl_xor(p1, off, 64);
    }
    if (c == 0) {
        out[(size_t)node * 2 + 0] = p0 + bc[0];
        out[(size_t)node * 2 + 1] = p1 + bc[1];
    }
}

extern "C" void kernel_launch(void* const* d_in, const int* in_sizes, int n_in,
                              void* d_out, int out_size, void* d_ws, size_t ws_size,
                              hipStream_t stream) {
    const float* x   = (const float*)d_in[0];
    const int*   ei  = (const int*)d_in[1];     // int64 or int32, detected per block
    const float* W1  = (const float*)d_in[2];
    const float* a1s = (const float*)d_in[3];
    const float* a1d = (const float*)d_in[4];
    const float* b1  = (const float*)d_in[5];
    const float* W2  = (const float*)d_in[6];
    const float* a2s = (const float*)d_in[7];
    const float* a2d = (const float*)d_in[8];
    const float* b2  = (const float*)d_in[9];
    const float* Wc  = (const float*)d_in[10];
    const float* bc  = (const float*)d_in[11];
    float* out = (float*)d_out;
    (void)n_in; (void)out_size; (void)ws_size;

    int n = in_sizes[0] / 8;   // 50000
    int E = in_sizes[1] / 2;   // 800000

    char* ws = (char*)d_ws;
    size_t o = 0;
    auto carve = [&](size_t bytes) -> char* {
        char* p = ws + o;
        o = (o + bytes + 255) & ~(size_t)255;
        return p;
    };
    float* hout = (float*)carve((size_t)n * 256 * 4);
    float* h2   = (float*)carve((size_t)n * 64 * 4);
    float* aS   = (float*)carve((size_t)n * 4 * 4);
    float* aD   = (float*)carve((size_t)n * 4 * 4);
    int*   deg  = (int*)carve((size_t)n * 4);
    int*   offs = (int*)carve((size_t)(n + 1) * 4);
    int*   cur  = (int*)carve((size_t)n * 4);
    int*   ssrc = (int*)carve((size_t)E * 4);
    int*   bsum = (int*)carve(64 * 4);
    float* A2S  = (float*)carve((size_t)n * 4);
    float* A2D  = (float*)carve((size_t)n * 4);

    k1_alpha<<<(n + 255) / 256, 256, 0, stream>>>(x, W1, a1s, a1d, aS, aD, deg, n);
    k2_count<<<(E + 255) / 256, 256, 0, stream>>>(ei, E, deg);
    int nb = (n + 1023) / 1024;
    scan_block<<<nb, 1024, 0, stream>>>(deg, n, offs, bsum);
    scan_small<<<1, 64, 0, stream>>>(bsum, nb);
    scan_add<<<(n + 255) / 256, 256, 0, stream>>>(offs, bsum, cur, n, nb);
    k4_scatter<<<(E + 255) / 256, 256, 0, stream>>>(ei, E, cur, ssrc);
    k5_agg1<<<(n + 3) / 4, 256, 0, stream>>>(x, aS, aD, offs, ssrc, W1, b1, hout, n);
    k6_gemm<<<(n + 31) / 32, 256, 0, stream>>>(hout, W2, a2s, a2d, h2, A2S, A2D, n);
    k7_agg2<<<(n + 3) / 4, 256, 0, stream>>>(h2, A2S, A2D, offs, ssrc, b2, Wc, bc, out, n);
}

// Round 7
// 275.673 us; speedup vs baseline: 1.5974x; 1.1683x over previous
//
#include <hip/hip_runtime.h>
#include <hip/hip_bf16.h>

// ---------------------------------------------------------------------------
// VenomGNN: 2-layer GAT (4 heads x 64, then 1 head x 64) + linear classifier.
// Layer-1 aggregation uses linearity of h1 = x@W1 (h1 never materialized).
// Layer-1 output hout is emitted as bf16 hi/lo planes; the h2 = hout@W2 GEMM
// runs on MFMA (3-product bf16 split, error ~2^-18 per term). dst-CSR built
// once, reused by both layers. Softmax without max-shift (shift-invariant).
// ---------------------------------------------------------------------------

typedef __attribute__((ext_vector_type(8))) short bf16x8;
typedef __attribute__((ext_vector_type(4))) float f32x4;

__device__ __forceinline__ float lrelu(float e) { return e > 0.f ? e : 0.2f * e; }
__device__ __forceinline__ float eluf(float v)  { return v > 0.f ? v : (__expf(v) - 1.f); }

__device__ __forceinline__ void split_bf16(float v, unsigned short& hi, unsigned short& lo) {
    __hip_bfloat16 h = __float2bfloat16(v);
    float hf = __bfloat162float(h);
    __hip_bfloat16 l = __float2bfloat16(v - hf);
    hi = *reinterpret_cast<unsigned short*>(&h);
    lo = *reinterpret_cast<unsigned short*>(&l);
}

// Per-block edge-dtype detection (int64 ref dtype vs int32 staging): for
// int64 little-endian values < 2^31, every odd 32-bit word is 0.
__device__ __forceinline__ int detect_is64(const int* __restrict__ ei32, int* s_is64) {
    if (threadIdx.x < 64) {
        int w = ei32[2 * threadIdx.x + 1];
        unsigned long long b = __ballot(w != 0);
        if (threadIdx.x == 0) *s_is64 = (b == 0ull) ? 1 : 0;
    }
    __syncthreads();
    return *s_is64;
}

// K1: aS/aD [N,4] = x @ (W1 . a1s/d), folded 8x4 matrices recomputed per
// block into LDS. Also zeroes deg[] (saves a memset dispatch).
__global__ __launch_bounds__(256) void k1_alpha(
    const float* __restrict__ x, const float* __restrict__ W1,
    const float* __restrict__ a1s, const float* __restrict__ a1d,
    float* __restrict__ aS, float* __restrict__ aD, int* __restrict__ deg, int n) {
    __shared__ float sA1S[32], sA1D[32];
    int t = threadIdx.x;
    if (t < 64) {
        int k = (t & 31) >> 2, h = t & 3;
        const float* av = (t < 32) ? a1s : a1d;
        float ss = 0.f;
        for (int c = 0; c < 64; ++c)
            ss = fmaf(W1[k * 256 + h * 64 + c], av[h * 64 + c], ss);
        if (t < 32) sA1S[t] = ss; else sA1D[t - 32] = ss;
    }
    __syncthreads();
    int node = blockIdx.x * 256 + t;
    if (node >= n) return;
    deg[node] = 0;
    float4 xa = ((const float4*)x)[node * 2];
    float4 xb = ((const float4*)x)[node * 2 + 1];
    float xv[8] = {xa.x, xa.y, xa.z, xa.w, xb.x, xb.y, xb.z, xb.w};
    float s[4], d[4];
#pragma unroll
    for (int h = 0; h < 4; ++h) {
        float ss = 0.f, sd = 0.f;
#pragma unroll
        for (int k = 0; k < 8; ++k) {
            ss = fmaf(xv[k], sA1S[k * 4 + h], ss);
            sd = fmaf(xv[k], sA1D[k * 4 + h], sd);
        }
        s[h] = ss; d[h] = sd;
    }
    ((float4*)aS)[node] = make_float4(s[0], s[1], s[2], s[3]);
    ((float4*)aD)[node] = make_float4(d[0], d[1], d[2], d[3]);
}

// KB: pack W2 into per-lane MFMA B-fragments, bf16 hi/lo split.
// Fragment f = (split*8 + kstep)*4 + ntile; lane element i corresponds to
// k = kstep*32 + (lane>>4)*8 + i, col = ntile*16 + (lane&15). Stored as uint4.
__global__ __launch_bounds__(256) void kB_pack(
    const float* __restrict__ W2, uint4* __restrict__ Bpk) {
    int idx = blockIdx.x * 256 + threadIdx.x;   // [0, 4096)
    int lane = idx & 63, rest = idx >> 6;       // rest in [0,64)
    int nt = rest & 3, ks = (rest >> 2) & 7, split = rest >> 5;
    unsigned short vals[8];
#pragma unroll
    for (int i = 0; i < 8; ++i) {
        int k = ks * 32 + (lane >> 4) * 8 + i;
        int col = nt * 16 + (lane & 15);
        unsigned short hi, lo;
        split_bf16(W2[k * 64 + col], hi, lo);
        vals[i] = split ? lo : hi;
    }
    uint4 w;
    w.x = (unsigned)vals[0] | ((unsigned)vals[1] << 16);
    w.y = (unsigned)vals[2] | ((unsigned)vals[3] << 16);
    w.z = (unsigned)vals[4] | ((unsigned)vals[5] << 16);
    w.w = (unsigned)vals[6] | ((unsigned)vals[7] << 16);
    Bpk[rest * 64 + lane] = w;
}

// K2: in-degree histogram over real edges (low-dword reads only).
__global__ __launch_bounds__(256) void k2_count(
    const int* __restrict__ ei32, int E, int* __restrict__ deg) {
    __shared__ int sf;
    int is64 = detect_is64(ei32, &sf);
    int e = blockIdx.x * 256 + threadIdx.x;
    if (e < E) {
        int d = is64 ? ei32[(E + e) * 2] : ei32[E + e];
        atomicAdd(&deg[d], 1);
    }
}

// K3a: per-1024-chunk exclusive scan + chunk totals.
__global__ __launch_bounds__(1024) void scan_block(
    const int* __restrict__ deg, int n, int* __restrict__ offs, int* __restrict__ bsum) {
    int t = threadIdx.x;
    int i = blockIdx.x * 1024 + t;
    int v = (i < n) ? deg[i] : 0;
    int lane = t & 63, w = t >> 6;
    int s = v;
#pragma unroll
    for (int off = 1; off < 64; off <<= 1) {
        int u = __shfl_up(s, off, 64);
        if (lane >= off) s += u;
    }
    __shared__ int wsums[16];
    if (lane == 63) wsums[w] = s;
    __syncthreads();
    if (t < 16) {
        int wv = wsums[t];
#pragma unroll
        for (int off = 1; off < 16; off <<= 1) {
            int u = __shfl_up(wv, off, 64);
            if (t >= off) wv += u;
        }
        wsums[t] = wv;
    }
    __syncthreads();
    int waveoff = (w == 0) ? 0 : wsums[w - 1];
    if (i < n) offs[i] = s + waveoff - v;          // block-local exclusive
    if (t == 1023) bsum[blockIdx.x] = s + waveoff; // block total
}

// K3b: inclusive scan of <=64 chunk totals (single wave).
__global__ void scan_small(int* __restrict__ bsum, int nb) {
    int t = threadIdx.x;
    int v = (t < nb) ? bsum[t] : 0;
#pragma unroll
    for (int off = 1; off < 64; off <<= 1) {
        int u = __shfl_up(v, off, 64);
        if (t >= off) v += u;
    }
    if (t < nb) bsum[t] = v;
}

// K3c: add chunk offsets; mirror into scatter cursors; write offs[n].
__global__ void scan_add(int* __restrict__ offs, const int* __restrict__ bsum,
                         int* __restrict__ cur, int n, int nb) {
    int i = blockIdx.x * blockDim.x + threadIdx.x;
    if (i < n) {
        int b = i >> 10;
        int val = offs[i] + (b ? bsum[b - 1] : 0);
        offs[i] = val;
        cur[i] = val;
    }
    if (i == 0) offs[n] = bsum[nb - 1];
}

// K4: bucket-scatter src ids into dst-CSR order.
__global__ __launch_bounds__(256) void k4_scatter(
    const int* __restrict__ ei32, int E, int* __restrict__ cur,
    int* __restrict__ ssrc) {
    __shared__ int sf;
    int is64 = detect_is64(ei32, &sf);
    int e = blockIdx.x * 256 + threadIdx.x;
    if (e < E) {
        int d = is64 ? ei32[(E + e) * 2] : ei32[E + e];
        int s = is64 ? ei32[e * 2] : ei32[e];
        int p = atomicAdd(&cur[d], 1);
        ssrc[p] = s;
    }
}

// K5: GAT-1 via linearity. Wave = node; lane = eslot*4 + h. Accumulates
// vec[h][8] = sum_e exp(e)*x[src], denom[h]; xor-reduce across eslots;
// self-loop post-reduction; out[h*64+c] = ELU((vec[h].W1col)*inv[h] + b1)
// written as bf16 hi/lo planes for the MFMA GEMM downstream.
__global__ __launch_bounds__(256) void k5_agg1(
    const float* __restrict__ x, const float* __restrict__ aS,
    const float* __restrict__ aD, const int* __restrict__ offs,
    const int* __restrict__ ssrc, const float* __restrict__ W1,
    const float* __restrict__ b1, unsigned short* __restrict__ hhi,
    unsigned short* __restrict__ hlo, int n) {
    int node = blockIdx.x * 4 + (threadIdx.x >> 6);
    if (node >= n) return;
    int lane = threadIdx.x & 63;
    int h = lane & 3, eslot = lane >> 2;
    int s0 = offs[node], s1 = offs[node + 1];
    float ad = aD[node * 4 + h];
    float denom = 0.f;
    float vec[8] = {0.f, 0.f, 0.f, 0.f, 0.f, 0.f, 0.f, 0.f};
    const float4* xv = (const float4*)x;
    for (int e = s0 + eslot; e < s1; e += 16) {
        int s = ssrc[e];
        float ex = __expf(lrelu(aS[s * 4 + h] + ad));
        denom += ex;
        float4 xa = xv[s * 2];
        float4 xb = xv[s * 2 + 1];
        vec[0] = fmaf(ex, xa.x, vec[0]); vec[1] = fmaf(ex, xa.y, vec[1]);
        vec[2] = fmaf(ex, xa.z, vec[2]); vec[3] = fmaf(ex, xa.w, vec[3]);
        vec[4] = fmaf(ex, xb.x, vec[4]); vec[5] = fmaf(ex, xb.y, vec[5]);
        vec[6] = fmaf(ex, xb.z, vec[6]); vec[7] = fmaf(ex, xb.w, vec[7]);
    }
#pragma unroll
    for (int off = 4; off < 64; off <<= 1) {
        denom += __shfl_xor(denom, off, 64);
#pragma unroll
        for (int k = 0; k < 8; ++k) vec[k] += __shfl_xor(vec[k], off, 64);
    }
    float exs = __expf(lrelu(aS[node * 4 + h] + ad));
    denom += exs;
    float4 xa = xv[node * 2];
    float4 xb = xv[node * 2 + 1];
    vec[0] = fmaf(exs, xa.x, vec[0]); vec[1] = fmaf(exs, xa.y, vec[1]);
    vec[2] = fmaf(exs, xa.z, vec[2]); vec[3] = fmaf(exs, xa.w, vec[3]);
    vec[4] = fmaf(exs, xb.x, vec[4]); vec[5] = fmaf(exs, xb.y, vec[5]);
    vec[6] = fmaf(exs, xb.z, vec[6]); vec[7] = fmaf(exs, xb.w, vec[7]);
    float vhk[4][8], invd[4];
#pragma unroll
    for (int hh = 0; hh < 4; ++hh) {
        invd[hh] = 1.f / (__shfl(denom, hh, 64) + 1e-16f);
#pragma unroll
        for (int k = 0; k < 8; ++k) vhk[hh][k] = __shfl(vec[k], hh, 64);
    }
#pragma unroll
    for (int hh = 0; hh < 4; ++hh) {
        int j = hh * 64 + lane;
        float dot = 0.f;
#pragma unroll
        for (int k = 0; k < 8; ++k) dot = fmaf(vhk[hh][k], W1[k * 256 + j], dot);
        float o = eluf(fmaf(dot, invd[hh], b1[j]));
        unsigned short hi, lo;
        split_bf16(o, hi, lo);
        hhi[(size_t)node * 256 + j] = hi;
        hlo[(size_t)node * 256 + j] = lo;
    }
}

// K6: h2 = hout @ W2 on MFMA (bf16 3-product split) + fused alpha2 dots.
// Block = 4 waves x 16 nodes = 64 nodes; per wave: 4 col-tiles x 8 k-steps
// x 3 split-products = 96 mfma_f32_16x16x32_bf16; no LDS.
// A frag: row = lane&15, k = ks*32 + (lane>>4)*8 + i (contiguous 16B load).
// C/D frag: col = nt*16 + (lane&15), row = (lane>>4)*4 + reg.
__global__ __launch_bounds__(256) void k6_mfma(
    const unsigned short* __restrict__ hhi, const unsigned short* __restrict__ hlo,
    const uint4* __restrict__ Bpk, const float* __restrict__ a2s,
    const float* __restrict__ a2d, float* __restrict__ h2,
    float* __restrict__ A2S, float* __restrict__ A2D, int n) {
    int lane = threadIdx.x & 63;
    int row0 = blockIdx.x * 64 + (threadIdx.x >> 6) * 16;
    int r = row0 + (lane & 15);
    if (r >= n) r = n - 1;                       // clamp loads; stores guarded
    f32x4 acc[4];
#pragma unroll
    for (int nt = 0; nt < 4; ++nt) acc[nt] = {0.f, 0.f, 0.f, 0.f};
#pragma unroll
    for (int ks = 0; ks < 8; ++ks) {
        int koff = ks * 32 + (lane >> 4) * 8;
        bf16x8 ahi = *(const bf16x8*)(hhi + (size_t)r * 256 + koff);
        bf16x8 alo = *(const bf16x8*)(hlo + (size_t)r * 256 + koff);
#pragma unroll
        for (int nt = 0; nt < 4; ++nt) {
            uint4 bh = Bpk[(ks * 4 + nt) * 64 + lane];
            uint4 bl = Bpk[((8 + ks) * 4 + nt) * 64 + lane];
            bf16x8 bhi = *(bf16x8*)&bh;
            bf16x8 blo = *(bf16x8*)&bl;
            acc[nt] = __builtin_amdgcn_mfma_f32_16x16x32_bf16(ahi, bhi, acc[nt], 0, 0, 0);
            acc[nt] = __builtin_amdgcn_mfma_f32_16x16x32_bf16(ahi, blo, acc[nt], 0, 0, 0);
            acc[nt] = __builtin_amdgcn_mfma_f32_16x16x32_bf16(alo, bhi, acc[nt], 0, 0, 0);
        }
    }
    // h2 stores
#pragma unroll
    for (int nt = 0; nt < 4; ++nt) {
#pragma unroll
        for (int reg = 0; reg < 4; ++reg) {
            int row = row0 + (lane >> 4) * 4 + reg;
            if (row < n) h2[(size_t)row * 64 + nt * 16 + (lane & 15)] = acc[nt][reg];
        }
    }
    // fused A2S/A2D: per output row, dot over 64 cols
    float a2sv[4], a2dv[4];
#pragma unroll
    for (int nt = 0; nt < 4; ++nt) {
        a2sv[nt] = a2s[nt * 16 + (lane & 15)];
        a2dv[nt] = a2d[nt * 16 + (lane & 15)];
    }
#pragma unroll
    for (int reg = 0; reg < 4; ++reg) {
        float ps = 0.f, pd = 0.f;
#pragma unroll
        for (int nt = 0; nt < 4; ++nt) {
            ps = fmaf(acc[nt][reg], a2sv[nt], ps);
            pd = fmaf(acc[nt][reg], a2dv[nt], pd);
        }
#pragma unroll
        for (int off = 1; off < 16; off <<= 1) {
            ps += __shfl_xor(ps, off, 64);
            pd += __shfl_xor(pd, off, 64);
        }
        int row = row0 + (lane >> 4) * 4 + reg;
        if ((lane & 15) == 0 && row < n) { A2S[row] = ps; A2D[row] = pd; }
    }
}

// K7: GAT-2 segment softmax + aggregate + bias + ELU + classifier (fused).
// Wave = node; lane c: edge-group g=c>>4, channel-quad q=c&15 (float4) ->
// 4 edges in flight; xor(16,32) cross-group reduce. No max-shift.
__global__ __launch_bounds__(256) void k7_agg2(
    const float* __restrict__ h2, const float* __restrict__ A2S,
    const float* __restrict__ A2D, const int* __restrict__ offs,
    const int* __restrict__ ssrc, const float* __restrict__ b2,
    const float* __restrict__ Wc, const float* __restrict__ bc,
    float* __restrict__ out, int n) {
    int node = blockIdx.x * 4 + (threadIdx.x >> 6);
    if (node >= n) return;
    int c = threadIdx.x & 63;
    int s0 = offs[node], s1 = offs[node + 1];
    float ad = A2D[node];
    int g = c >> 4, q = c & 15;
    const float4* h2v = (const float4*)h2;
    float denom = 0.f;
    float4 acc = make_float4(0.f, 0.f, 0.f, 0.f);
    for (int e = s0 + g; e < s1; e += 4) {
        int s = ssrc[e];
        float4 hv = h2v[(size_t)s * 16 + q];
        float ex = __expf(lrelu(A2S[s] + ad));
        denom += ex;
        acc.x = fmaf(ex, hv.x, acc.x); acc.y = fmaf(ex, hv.y, acc.y);
        acc.z = fmaf(ex, hv.z, acc.z); acc.w = fmaf(ex, hv.w, acc.w);
    }
#pragma unroll
    for (int off = 16; off <= 32; off <<= 1) {
        denom += __shfl_xor(denom, off, 64);
        acc.x += __shfl_xor(acc.x, off, 64);
        acc.y += __shfl_xor(acc.y, off, 64);
        acc.z += __shfl_xor(acc.z, off, 64);
        acc.w += __shfl_xor(acc.w, off, 64);
    }
    float exs = __expf(lrelu(A2S[node] + ad));
    denom += exs;
    float4 hS = h2v[(size_t)node * 16 + q];
    acc.x = fmaf(exs, hS.x, acc.x); acc.y = fmaf(exs, hS.y, acc.y);
    acc.z = fmaf(exs, hS.z, acc.z); acc.w = fmaf(exs, hS.w, acc.w);
    float inv = 1.f / (denom + 1e-16f);
    float4 bv = ((const float4*)b2)[q];
    float o0 = eluf(fmaf(acc.x, inv, bv.x));
    float o1 = eluf(fmaf(acc.y, inv, bv.y));
    float o2 = eluf(fmaf(acc.z, inv, bv.z));
    float o3 = eluf(fmaf(acc.w, inv, bv.w));
    int ch = q * 4;
    float p0 = o0 * Wc[ch * 2 + 0] + o1 * Wc[ch * 2 + 2] + o2 * Wc[ch * 2 + 4] + o3 * Wc[ch * 2 + 6];
    float p1 = o0 * Wc[ch * 2 + 1] + o1 * Wc[ch * 2 + 3] + o2 * Wc[ch * 2 + 5] + o3 * Wc[ch * 2 + 7];
#pragma unroll
    for (int off = 8; off > 0; off >>= 1) {
        p0 += __shfl_xor(p0, off, 64);
        p1 += __shfl_xor(p1, off, 64);
    }
    if (c == 0) {
        out[(size_t)node * 2 + 0] = p0 + bc[0];
        out[(size_t)node * 2 + 1] = p1 + bc[1];
    }
}

extern "C" void kernel_launch(void* const* d_in, const int* in_sizes, int n_in,
                              void* d_out, int out_size, void* d_ws, size_t ws_size,
                              hipStream_t stream) {
    const float* x   = (const float*)d_in[0];
    const int*   ei  = (const int*)d_in[1];     // int64 or int32, detected per block
    const float* W1  = (const float*)d_in[2];
    const float* a1s = (const float*)d_in[3];
    const float* a1d = (const float*)d_in[4];
    const float* b1  = (const float*)d_in[5];
    const float* W2  = (const float*)d_in[6];
    const float* a2s = (const float*)d_in[7];
    const float* a2d = (const float*)d_in[8];
    const float* b2  = (const float*)d_in[9];
    const float* Wc  = (const float*)d_in[10];
    const float* bc  = (const float*)d_in[11];
    float* out = (float*)d_out;
    (void)n_in; (void)out_size; (void)ws_size;

    int n = in_sizes[0] / 8;   // 50000
    int E = in_sizes[1] / 2;   // 800000

    char* ws = (char*)d_ws;
    size_t o = 0;
    auto carve = [&](size_t bytes) -> char* {
        char* p = ws + o;
        o = (o + bytes + 255) & ~(size_t)255;
        return p;
    };
    unsigned short* hhi = (unsigned short*)carve((size_t)n * 256 * 2);
    unsigned short* hlo = (unsigned short*)carve((size_t)n * 256 * 2);
    float* h2   = (float*)carve((size_t)n * 64 * 4);
    float* aS   = (float*)carve((size_t)n * 4 * 4);
    float* aD   = (float*)carve((size_t)n * 4 * 4);
    int*   deg  = (int*)carve((size_t)n * 4);
    int*   offs = (int*)carve((size_t)(n + 1) * 4);
    int*   cur  = (int*)carve((size_t)n * 4);
    int*   ssrc = (int*)carve((size_t)E * 4);
    int*   bsum = (int*)carve(64 * 4);
    uint4* Bpk  = (uint4*)carve(4096 * 16);
    float* A2S  = (float*)carve((size_t)n * 4);
    float* A2D  = (float*)carve((size_t)n * 4);

    k1_alpha<<<(n + 255) / 256, 256, 0, stream>>>(x, W1, a1s, a1d, aS, aD, deg, n);
    kB_pack<<<16, 256, 0, stream>>>(W2, Bpk);
    k2_count<<<(E + 255) / 256, 256, 0, stream>>>(ei, E, deg);
    int nb = (n + 1023) / 1024;
    scan_block<<<nb, 1024, 0, stream>>>(deg, n, offs, bsum);
    scan_small<<<1, 64, 0, stream>>>(bsum, nb);
    scan_add<<<(n + 255) / 256, 256, 0, stream>>>(offs, bsum, cur, n, nb);
    k4_scatter<<<(E + 255) / 256, 256, 0, stream>>>(ei, E, cur, ssrc);
    k5_agg1<<<(n + 3) / 4, 256, 0, stream>>>(x, aS, aD, offs, ssrc, W1, b1, hhi, hlo, n);
    k6_mfma<<<(n + 63) / 64, 256, 0, stream>>>(hhi, hlo, Bpk, a2s, a2d, h2, A2S, A2D, n);
    k7_agg2<<<(n + 3) / 4, 256, 0, stream>>>(h2, A2S, A2D, offs, ssrc, b2, Wc, bc, out, n);
}

// Round 11
// 273.035 us; speedup vs baseline: 1.6128x; 1.0097x over previous
//
#include <hip/hip_runtime.h>
#include <hip/hip_bf16.h>

// ---------------------------------------------------------------------------
// VenomGNN: 2-layer GAT (4 heads x 64, then 1 head x 64) + linear classifier.
// - Layer-1 aggregation via linearity of h1 = x@W1 (h1 never materialized).
// - Layer-1 output emitted as bf16 hi/lo planes; h2 = hout@W2 runs on MFMA
//   (3-product bf16 split, ~2^-18 rel error).
// - dst-CSR built once, reused by both layers. CSR build is XCD-range
//   partitioned: block (chunk, r=bid&7) handles only dst range r, so cursor
//   atomics and ssrc writes stay local to one XCD's L2 (kills the 16x write
//   amplification measured in round 7: WRITE_SIZE 52.6MB for 3.2MB payload).
// - Softmax without max-shift (shift-invariant; exponents bounded).
// ---------------------------------------------------------------------------

typedef __attribute__((ext_vector_type(8))) short bf16x8;
typedef __attribute__((ext_vector_type(4))) float f32x4;

__device__ __forceinline__ float lrelu(float e) { return e > 0.f ? e : 0.2f * e; }
__device__ __forceinline__ float eluf(float v)  { return v > 0.f ? v : (__expf(v) - 1.f); }

__device__ __forceinline__ void split_bf16(float v, unsigned short& hi, unsigned short& lo) {
    __hip_bfloat16 h = __float2bfloat16(v);
    float hf = __bfloat162float(h);
    __hip_bfloat16 l = __float2bfloat16(v - hf);
    hi = *reinterpret_cast<unsigned short*>(&h);
    lo = *reinterpret_cast<unsigned short*>(&l);
}

// Per-block edge-dtype detection (int64 ref dtype vs int32 staging): for
// int64 little-endian values < 2^31, every odd 32-bit word is 0.
__device__ __forceinline__ int detect_is64(const int* __restrict__ ei32, int* s_is64) {
    if (threadIdx.x < 64) {
        int w = ei32[2 * threadIdx.x + 1];
        unsigned long long b = __ballot(w != 0);
        if (threadIdx.x == 0) *s_is64 = (b == 0ull) ? 1 : 0;
    }
    __syncthreads();
    return *s_is64;
}

// K1: aS/aD [N,4] = x @ (W1 . a1s/d), folded 8x4 matrices recomputed per
// block into LDS. Also zeroes deg[] (saves a memset dispatch).
__global__ __launch_bounds__(256) void k1_alpha(
    const float* __restrict__ x, const float* __restrict__ W1,
    const float* __restrict__ a1s, const float* __restrict__ a1d,
    float* __restrict__ aS, float* __restrict__ aD, int* __restrict__ deg, int n) {
    __shared__ float sA1S[32], sA1D[32];
    int t = threadIdx.x;
    if (t < 64) {
        int k = (t & 31) >> 2, h = t & 3;
        const float* av = (t < 32) ? a1s : a1d;
        float ss = 0.f;
        for (int c = 0; c < 64; ++c)
            ss = fmaf(W1[k * 256 + h * 64 + c], av[h * 64 + c], ss);
        if (t < 32) sA1S[t] = ss; else sA1D[t - 32] = ss;
    }
    __syncthreads();
    int node = blockIdx.x * 256 + t;
    if (node >= n) return;
    deg[node] = 0;
    float4 xa = ((const float4*)x)[node * 2];
    float4 xb = ((const float4*)x)[node * 2 + 1];
    float xv[8] = {xa.x, xa.y, xa.z, xa.w, xb.x, xb.y, xb.z, xb.w};
    float s[4], d[4];
#pragma unroll
    for (int h = 0; h < 4; ++h) {
        float ss = 0.f, sd = 0.f;
#pragma unroll
        for (int k = 0; k < 8; ++k) {
            ss = fmaf(xv[k], sA1S[k * 4 + h], ss);
            sd = fmaf(xv[k], sA1D[k * 4 + h], sd);
        }
        s[h] = ss; d[h] = sd;
    }
    ((float4*)aS)[node] = make_float4(s[0], s[1], s[2], s[3]);
    ((float4*)aD)[node] = make_float4(d[0], d[1], d[2], d[3]);
}

// KB: pack W2 into per-lane MFMA B-fragments, bf16 hi/lo split.
__global__ __launch_bounds__(256) void kB_pack(
    const float* __restrict__ W2, uint4* __restrict__ Bpk) {
    int idx = blockIdx.x * 256 + threadIdx.x;   // [0, 4096)
    int lane = idx & 63, rest = idx >> 6;       // rest in [0,64)
    int nt = rest & 3, ks = (rest >> 2) & 7, split = rest >> 5;
    unsigned short vals[8];
#pragma unroll
    for (int i = 0; i < 8; ++i) {
        int k = ks * 32 + (lane >> 4) * 8 + i;
        int col = nt * 16 + (lane & 15);
        unsigned short hi, lo;
        split_bf16(W2[k * 64 + col], hi, lo);
        vals[i] = split ? lo : hi;
    }
    uint4 w;
    w.x = (unsigned)vals[0] | ((unsigned)vals[1] << 16);
    w.y = (unsigned)vals[2] | ((unsigned)vals[3] << 16);
    w.z = (unsigned)vals[4] | ((unsigned)vals[5] << 16);
    w.w = (unsigned)vals[6] | ((unsigned)vals[7] << 16);
    Bpk[rest * 64 + lane] = w;
}

// KC: compact edge src/dst into int32 arrays (one read of the int64 list).
__global__ __launch_bounds__(256) void kc_compact(
    const int* __restrict__ ei32, int E, int* __restrict__ sdst,
    int* __restrict__ ssrc0) {
    __shared__ int sf;
    int is64 = detect_is64(ei32, &sf);
    int base = blockIdx.x * 2048 + threadIdx.x;
#pragma unroll
    for (int j = 0; j < 8; ++j) {
        int e = base + j * 256;
        if (e < E) {
            if (is64) {
                sdst[e] = ei32[(size_t)(E + e) * 2];
                ssrc0[e] = ei32[(size_t)e * 2];
            } else {
                sdst[e] = ei32[E + e];
                ssrc0[e] = ei32[e];
            }
        }
    }
}

// Range id of a dst node (8 contiguous ranges of rpb nodes).
__device__ __forceinline__ int range_of(int d, int rpb) {
    return (d >= rpb) + (d >= 2 * rpb) + (d >= 3 * rpb) + (d >= 4 * rpb)
         + (d >= 5 * rpb) + (d >= 6 * rpb) + (d >= 7 * rpb);
}

// K2R: XCD-range-partitioned in-degree histogram. Block (c, rr=bid&7)
// processes chunk c but counts only dst in range rr -> deg slice (25KB)
// stays hot in XCD rr's L2 (bid%8 == XCD under round-robin dispatch).
__global__ __launch_bounds__(256) void k2r_count(
    const int* __restrict__ sdst, int E, int rpb, int* __restrict__ deg) {
    int rr = blockIdx.x & 7;
    int base = (blockIdx.x >> 3) * 2048 + threadIdx.x;
#pragma unroll
    for (int j = 0; j < 8; ++j) {
        int e = base + j * 256;
        if (e < E) {
            int d = sdst[e];
            if (range_of(d, rpb) == rr) atomicAdd(&deg[d], 1);
        }
    }
}

// K3a: per-1024-chunk exclusive scan + chunk totals.
__global__ __launch_bounds__(1024) void scan_block(
    const int* __restrict__ deg, int n, int* __restrict__ offs, int* __restrict__ bsum) {
    int t = threadIdx.x;
    int i = blockIdx.x * 1024 + t;
    int v = (i < n) ? deg[i] : 0;
    int lane = t & 63, w = t >> 6;
    int s = v;
#pragma unroll
    for (int off = 1; off < 64; off <<= 1) {
        int u = __shfl_up(s, off, 64);
        if (lane >= off) s += u;
    }
    __shared__ int wsums[16];
    if (lane == 63) wsums[w] = s;
    __syncthreads();
    if (t < 16) {
        int wv = wsums[t];
#pragma unroll
        for (int off = 1; off < 16; off <<= 1) {
            int u = __shfl_up(wv, off, 64);
            if (t >= off) wv += u;
        }
        wsums[t] = wv;
    }
    __syncthreads();
    int waveoff = (w == 0) ? 0 : wsums[w - 1];
    if (i < n) offs[i] = s + waveoff - v;          // block-local exclusive
    if (t == 1023) bsum[blockIdx.x] = s + waveoff; // block total
}

// K3b: inclusive scan of <=64 chunk totals (single wave).
__global__ void scan_small(int* __restrict__ bsum, int nb) {
    int t = threadIdx.x;
    int v = (t < nb) ? bsum[t] : 0;
#pragma unroll
    for (int off = 1; off < 64; off <<= 1) {
        int u = __shfl_up(v, off, 64);
        if (t >= off) v += u;
    }
    if (t < nb) bsum[t] = v;
}

// K3c: add chunk offsets; mirror into scatter cursors; write offs[n].
__global__ void scan_add(int* __restrict__ offs, const int* __restrict__ bsum,
                         int* __restrict__ cur, int n, int nb) {
    int i = blockIdx.x * blockDim.x + threadIdx.x;
    if (i < n) {
        int b = i >> 10;
        int val = offs[i] + (b ? bsum[b - 1] : 0);
        offs[i] = val;
        cur[i] = val;
    }
    if (i == 0) offs[n] = bsum[nb - 1];
}

// K4R: XCD-range-partitioned bucket-scatter. Same (chunk, range) layout as
// K2R: cursor atomics L2-local; ssrc writes land in a dense 400KB region
// written only from one XCD -> lines fill while resident (no amplification).
__global__ __launch_bounds__(256) void k4r_scatter(
    const int* __restrict__ sdst, const int* __restrict__ ssrc0, int E,
    int rpb, int* __restrict__ cur, int* __restrict__ ssrc) {
    int rr = blockIdx.x & 7;
    int base = (blockIdx.x >> 3) * 2048 + threadIdx.x;
#pragma unroll
    for (int j = 0; j < 8; ++j) {
        int e = base + j * 256;
        if (e < E) {
            int d = sdst[e];
            if (range_of(d, rpb) == rr) {
                int p = atomicAdd(&cur[d], 1);
                ssrc[p] = ssrc0[e];
            }
        }
    }
}

// K5: GAT-1 via linearity. Wave = node; lane = eslot*4 + h. Accumulates
// vec[h][8] = sum_e exp(e)*x[src], denom[h]; xor-reduce across eslots;
// self-loop post-reduction; out[h*64+c] = ELU((vec[h].W1col)*inv[h] + b1)
// written as bf16 hi/lo planes for the MFMA GEMM downstream.
__global__ __launch_bounds__(256) void k5_agg1(
    const float* __restrict__ x, const float* __restrict__ aS,
    const float* __restrict__ aD, const int* __restrict__ offs,
    const int* __restrict__ ssrc, const float* __restrict__ W1,
    const float* __restrict__ b1, unsigned short* __restrict__ hhi,
    unsigned short* __restrict__ hlo, int n) {
    int node = blockIdx.x * 4 + (threadIdx.x >> 6);
    if (node >= n) return;
    int lane = threadIdx.x & 63;
    int h = lane & 3, eslot = lane >> 2;
    int s0 = offs[node], s1 = offs[node + 1];
    float ad = aD[node * 4 + h];
    float denom = 0.f;
    float vec[8] = {0.f, 0.f, 0.f, 0.f, 0.f, 0.f, 0.f, 0.f};
    const float4* xv = (const float4*)x;
    for (int e = s0 + eslot; e < s1; e += 16) {
        int s = ssrc[e];
        float ex = __expf(lrelu(aS[s * 4 + h] + ad));
        denom += ex;
        float4 xa = xv[s * 2];
        float4 xb = xv[s * 2 + 1];
        vec[0] = fmaf(ex, xa.x, vec[0]); vec[1] = fmaf(ex, xa.y, vec[1]);
        vec[2] = fmaf(ex, xa.z, vec[2]); vec[3] = fmaf(ex, xa.w, vec[3]);
        vec[4] = fmaf(ex, xb.x, vec[4]); vec[5] = fmaf(ex, xb.y, vec[5]);
        vec[6] = fmaf(ex, xb.z, vec[6]); vec[7] = fmaf(ex, xb.w, vec[7]);
    }
#pragma unroll
    for (int off = 4; off < 64; off <<= 1) {
        denom += __shfl_xor(denom, off, 64);
#pragma unroll
        for (int k = 0; k < 8; ++k) vec[k] += __shfl_xor(vec[k], off, 64);
    }
    float exs = __expf(lrelu(aS[node * 4 + h] + ad));
    denom += exs;
    float4 xa = xv[node * 2];
    float4 xb = xv[node * 2 + 1];
    vec[0] = fmaf(exs, xa.x, vec[0]); vec[1] = fmaf(exs, xa.y, vec[1]);
    vec[2] = fmaf(exs, xa.z, vec[2]); vec[3] = fmaf(exs, xa.w, vec[3]);
    vec[4] = fmaf(exs, xb.x, vec[4]); vec[5] = fmaf(exs, xb.y, vec[5]);
    vec[6] = fmaf(exs, xb.z, vec[6]); vec[7] = fmaf(exs, xb.w, vec[7]);
    float vhk[4][8], invd[4];
#pragma unroll
    for (int hh = 0; hh < 4; ++hh) {
        invd[hh] = 1.f / (__shfl(denom, hh, 64) + 1e-16f);
#pragma unroll
        for (int k = 0; k < 8; ++k) vhk[hh][k] = __shfl(vec[k], hh, 64);
    }
#pragma unroll
    for (int hh = 0; hh < 4; ++hh) {
        int j = hh * 64 + lane;
        float dot = 0.f;
#pragma unroll
        for (int k = 0; k < 8; ++k) dot = fmaf(vhk[hh][k], W1[k * 256 + j], dot);
        float o = eluf(fmaf(dot, invd[hh], b1[j]));
        unsigned short hi, lo;
        split_bf16(o, hi, lo);
        hhi[(size_t)node * 256 + j] = hi;
        hlo[(size_t)node * 256 + j] = lo;
    }
}

// K6: h2 = hout @ W2 on MFMA (bf16 3-product split) + fused alpha2 dots.
// Block = 4 waves x 16 nodes = 64 nodes; per wave: 4 col-tiles x 8 k-steps
// x 3 split-products = 96 mfma_f32_16x16x32_bf16; no LDS.
__global__ __launch_bounds__(256) void k6_mfma(
    const unsigned short* __restrict__ hhi, const unsigned short* __restrict__ hlo,
    const uint4* __restrict__ Bpk, const float* __restrict__ a2s,
    const float* __restrict__ a2d, float* __restrict__ h2,
    float* __restrict__ A2S, float* __restrict__ A2D, int n) {
    int lane = threadIdx.x & 63;
    int row0 = blockIdx.x * 64 + (threadIdx.x >> 6) * 16;
    int r = row0 + (lane & 15);
    if (r >= n) r = n - 1;                       // clamp loads; stores guarded
    f32x4 acc[4];
#pragma unroll
    for (int nt = 0; nt < 4; ++nt) acc[nt] = {0.f, 0.f, 0.f, 0.f};
#pragma unroll
    for (int ks = 0; ks < 8; ++ks) {
        int koff = ks * 32 + (lane >> 4) * 8;
        bf16x8 ahi = *(const bf16x8*)(hhi + (size_t)r * 256 + koff);
        bf16x8 alo = *(const bf16x8*)(hlo + (size_t)r * 256 + koff);
#pragma unroll
        for (int nt = 0; nt < 4; ++nt) {
            uint4 bh = Bpk[(ks * 4 + nt) * 64 + lane];
            uint4 bl = Bpk[((8 + ks) * 4 + nt) * 64 + lane];
            bf16x8 bhi = *(bf16x8*)&bh;
            bf16x8 blo = *(bf16x8*)&bl;
            acc[nt] = __builtin_amdgcn_mfma_f32_16x16x32_bf16(ahi, bhi, acc[nt], 0, 0, 0);
            acc[nt] = __builtin_amdgcn_mfma_f32_16x16x32_bf16(ahi, blo, acc[nt], 0, 0, 0);
            acc[nt] = __builtin_amdgcn_mfma_f32_16x16x32_bf16(alo, bhi, acc[nt], 0, 0, 0);
        }
    }
#pragma unroll
    for (int nt = 0; nt < 4; ++nt) {
#pragma unroll
        for (int reg = 0; reg < 4; ++reg) {
            int row = row0 + (lane >> 4) * 4 + reg;
            if (row < n) h2[(size_t)row * 64 + nt * 16 + (lane & 15)] = acc[nt][reg];
        }
    }
    float a2sv[4], a2dv[4];
#pragma unroll
    for (int nt = 0; nt < 4; ++nt) {
        a2sv[nt] = a2s[nt * 16 + (lane & 15)];
        a2dv[nt] = a2d[nt * 16 + (lane & 15)];
    }
#pragma unroll
    for (int reg = 0; reg < 4; ++reg) {
        float ps = 0.f, pd = 0.f;
#pragma unroll
        for (int nt = 0; nt < 4; ++nt) {
            ps = fmaf(acc[nt][reg], a2sv[nt], ps);
            pd = fmaf(acc[nt][reg], a2dv[nt], pd);
        }
#pragma unroll
        for (int off = 1; off < 16; off <<= 1) {
            ps += __shfl_xor(ps, off, 64);
            pd += __shfl_xor(pd, off, 64);
        }
        int row = row0 + (lane >> 4) * 4 + reg;
        if ((lane & 15) == 0 && row < n) { A2S[row] = ps; A2D[row] = pd; }
    }
}

// K7: GAT-2 segment softmax + aggregate + bias + ELU + classifier (fused).
// Wave = node; lane c: edge-group g=c>>4, channel-quad q=c&15 (float4) ->
// 4 edges in flight; xor(16,32) cross-group reduce. No max-shift.
__global__ __launch_bounds__(256) void k7_agg2(
    const float* __restrict__ h2, const float* __restrict__ A2S,
    const float* __restrict__ A2D, const int* __restrict__ offs,
    const int* __restrict__ ssrc, const float* __restrict__ b2,
    const float* __restrict__ Wc, const float* __restrict__ bc,
    float* __restrict__ out, int n) {
    int node = blockIdx.x * 4 + (threadIdx.x >> 6);
    if (node >= n) return;
    int c = threadIdx.x & 63;
    int s0 = offs[node], s1 = offs[node + 1];
    float ad = A2D[node];
    int g = c >> 4, q = c & 15;
    const float4* h2v = (const float4*)h2;
    float denom = 0.f;
    float4 acc = make_float4(0.f, 0.f, 0.f, 0.f);
    for (int e = s0 + g; e < s1; e += 4) {
        int s = ssrc[e];
        float4 hv = h2v[(size_t)s * 16 + q];
        float ex = __expf(lrelu(A2S[s] + ad));
        denom += ex;
        acc.x = fmaf(ex, hv.x, acc.x); acc.y = fmaf(ex, hv.y, acc.y);
        acc.z = fmaf(ex, hv.z, acc.z); acc.w = fmaf(ex, hv.w, acc.w);
    }
#pragma unroll
    for (int off = 16; off <= 32; off <<= 1) {
        denom += __shfl_xor(denom, off, 64);
        acc.x += __shfl_xor(acc.x, off, 64);
        acc.y += __shfl_xor(acc.y, off, 64);
        acc.z += __shfl_xor(acc.z, off, 64);
        acc.w += __shfl_xor(acc.w, off, 64);
    }
    float exs = __expf(lrelu(A2S[node] + ad));
    denom += exs;
    float4 hS = h2v[(size_t)node * 16 + q];
    acc.x = fmaf(exs, hS.x, acc.x); acc.y = fmaf(exs, hS.y, acc.y);
    acc.z = fmaf(exs, hS.z, acc.z); acc.w = fmaf(exs, hS.w, acc.w);
    float inv = 1.f / (denom + 1e-16f);
    float4 bv = ((const float4*)b2)[q];
    float o0 = eluf(fmaf(acc.x, inv, bv.x));
    float o1 = eluf(fmaf(acc.y, inv, bv.y));
    float o2 = eluf(fmaf(acc.z, inv, bv.z));
    float o3 = eluf(fmaf(acc.w, inv, bv.w));
    int ch = q * 4;
    float p0 = o0 * Wc[ch * 2 + 0] + o1 * Wc[ch * 2 + 2] + o2 * Wc[ch * 2 + 4] + o3 * Wc[ch * 2 + 6];
    float p1 = o0 * Wc[ch * 2 + 1] + o1 * Wc[ch * 2 + 3] + o2 * Wc[ch * 2 + 5] + o3 * Wc[ch * 2 + 7];
#pragma unroll
    for (int off = 8; off > 0; off >>= 1) {
        p0 += __shfl_xor(p0, off, 64);
        p1 += __shfl_xor(p1, off, 64);
    }
    if (c == 0) {
        out[(size_t)node * 2 + 0] = p0 + bc[0];
        out[(size_t)node * 2 + 1] = p1 + bc[1];
    }
}

extern "C" void kernel_launch(void* const* d_in, const int* in_sizes, int n_in,
                              void* d_out, int out_size, void* d_ws, size_t ws_size,
                              hipStream_t stream) {
    const float* x   = (const float*)d_in[0];
    const int*   ei  = (const int*)d_in[1];     // int64 or int32, detected per block
    const float* W1  = (const float*)d_in[2];
    const float* a1s = (const float*)d_in[3];
    const float* a1d = (const float*)d_in[4];
    const float* b1  = (const float*)d_in[5];
    const float* W2  = (const float*)d_in[6];
    const float* a2s = (const float*)d_in[7];
    const float* a2d = (const float*)d_in[8];
    const float* b2  = (const float*)d_in[9];
    const float* Wc  = (const float*)d_in[10];
    const float* bc  = (const float*)d_in[11];
    float* out = (float*)d_out;
    (void)n_in; (void)out_size; (void)ws_size;

    int n = in_sizes[0] / 8;   // 50000
    int E = in_sizes[1] / 2;   // 800000
    int rpb = (n + 7) / 8;     // nodes per XCD range

    char* ws = (char*)d_ws;
    size_t o = 0;
    auto carve = [&](size_t bytes) -> char* {
        char* p = ws + o;
        o = (o + bytes + 255) & ~(size_t)255;
        return p;
    };
    unsigned short* hhi = (unsigned short*)carve((size_t)n * 256 * 2);
    unsigned short* hlo = (unsigned short*)carve((size_t)n * 256 * 2);
    float* h2   = (float*)carve((size_t)n * 64 * 4);
    float* aS   = (float*)carve((size_t)n * 4 * 4);
    float* aD   = (float*)carve((size_t)n * 4 * 4);
    int*   deg  = (int*)carve((size_t)n * 4);
    int*   offs = (int*)carve((size_t)(n + 1) * 4);
    int*   cur  = (int*)carve((size_t)n * 4);
    int*   ssrc = (int*)carve((size_t)E * 4);
    int*   sdst = (int*)carve((size_t)E * 4);
    int*   ssrc0= (int*)carve((size_t)E * 4);
    int*   bsum = (int*)carve(64 * 4);
    uint4* Bpk  = (uint4*)carve(4096 * 16);
    float* A2S  = (float*)carve((size_t)n * 4);
    float* A2D  = (float*)carve((size_t)n * 4);

    int nchunk = (E + 2047) / 2048;
    k1_alpha<<<(n + 255) / 256, 256, 0, stream>>>(x, W1, a1s, a1d, aS, aD, deg, n);
    kB_pack<<<16, 256, 0, stream>>>(W2, Bpk);
    kc_compact<<<nchunk, 256, 0, stream>>>(ei, E, sdst, ssrc0);
    k2r_count<<<nchunk * 8, 256, 0, stream>>>(sdst, E, rpb, deg);
    int nb = (n + 1023) / 1024;
    scan_block<<<nb, 1024, 0, stream>>>(deg, n, offs, bsum);
    scan_small<<<1, 64, 0, stream>>>(bsum, nb);
    scan_add<<<(n + 255) / 256, 256, 0, stream>>>(offs, bsum, cur, n, nb);
    k4r_scatter<<<nchunk * 8, 256, 0, stream>>>(sdst, ssrc0, E, rpb, cur, ssrc);
    k5_agg1<<<(n + 3) / 4, 256, 0, stream>>>(x, aS, aD, offs, ssrc, W1, b1, hhi, hlo, n);
    k6_mfma<<<(n + 63) / 64, 256, 0, stream>>>(hhi, hlo, Bpk, a2s, a2d, h2, A2S, A2D, n);
    k7_agg2<<<(n + 3) / 4, 256, 0, stream>>>(h2, A2S, A2D, offs, ssrc, b2, Wc, bc, out, n);
}